// Round 3
// baseline (304.092 us; speedup 1.0000x reference)
//
#include <hip/hip_runtime.h>
#include <hip/hip_bf16.h>
#include <cstdint>
#include <cstddef>

typedef __attribute__((ext_vector_type(8))) short short8;
typedef __attribute__((ext_vector_type(4))) float f32x4;

#define MFMA16(a,b,c) __builtin_amdgcn_mfma_f32_16x16x32_bf16((a),(b),(c),0,0,0)
#define NEG_INF (-__builtin_inff())

__device__ __forceinline__ unsigned short f2bf(float f) {
    union { float f; unsigned int u; } a; a.f = f;
    return (unsigned short)((a.u + 0x7FFFu + ((a.u >> 16) & 1u)) >> 16);
}

// async global->LDS, 16B per lane. LDS dest = uniform base + lane*16.
__device__ __forceinline__ void gload16(const void* g, void* l) {
    __builtin_amdgcn_global_load_lds(
        (const __attribute__((address_space(1))) void*)g,
        (__attribute__((address_space(3))) void*)l, 16, 0, 0);
}

// ---------------- fused prep: X->bf16, 4x W-transpose, bias pack ----------------
// blocks [0,4096): convert X; [4096,8192): transpose W's; 8192: pack bias.
__global__ __launch_bounds__(256) void prep(const float* __restrict__ X,
                                            unsigned short* __restrict__ Xb,
                                            const float* __restrict__ Wq,
                                            const float* __restrict__ Wk,
                                            const float* __restrict__ Wv,
                                            const float* __restrict__ Wo,
                                            unsigned short* __restrict__ WqkvT,
                                            unsigned short* __restrict__ WoT,
                                            const float* __restrict__ bq,
                                            const float* __restrict__ bk,
                                            const float* __restrict__ bv,
                                            float* __restrict__ biasq) {
    const int bid = blockIdx.x;
    const int t = threadIdx.x;
    if (bid < 4096) {
        int i = (bid * 256 + t) * 4;
        float4 v = *(const float4*)(X + i);
        ushort4 o;
        o.x = f2bf(v.x); o.y = f2bf(v.y); o.z = f2bf(v.z); o.w = f2bf(v.w);
        *(ushort4*)(Xb + i) = o;
    } else if (bid < 8192) {
        __shared__ float tile[32][33];
        const int wid = bid - 4096;
        const int which = wid >> 10, t32 = wid & 1023;
        const float* W = (which == 0) ? Wq : (which == 1) ? Wk : (which == 2) ? Wv : Wo;
        unsigned short* WT = (which < 3) ? (WqkvT + which * 1048576) : WoT;
        int tx = t & 31, ty = t >> 5;
        int kb = (t32 & 31) * 32, nb = (t32 >> 5) * 32;
        #pragma unroll
        for (int r = 0; r < 32; r += 8)
            tile[ty + r][tx] = W[(size_t)(kb + ty + r) * 1024 + nb + tx];
        __syncthreads();
        #pragma unroll
        for (int r = 0; r < 32; r += 8) {
            float v = tile[tx][ty + r];
            WT[(size_t)(nb + ty + r) * 1024 + kb + tx] = f2bf(v);
        }
    } else {
        for (int i = t; i < 3072; i += 256) {
            const float* s = (i < 1024) ? bq : (i < 2048) ? bk : bv;
            biasq[i] = s[i & 1023];
        }
    }
}

// ---------------- V [32][2048][64] -> Vt [32][64][2048] (bf16) ----------------
__global__ __launch_bounds__(256) void transpose_v(const unsigned short* __restrict__ V,
                                                   unsigned short* __restrict__ Vt) {
    __shared__ unsigned short tl[64][65];
    int bh = blockIdx.x >> 5;
    int kt = blockIdx.x & 31;
    int t = threadIdx.x;
    int row = t >> 2, off = (t & 3) * 16;
    const unsigned short* src = V + ((size_t)bh * 2048 + kt * 64 + row) * 64 + off;
    uint4 d0 = *(const uint4*)src;
    uint4 d1 = *(const uint4*)(src + 8);
    unsigned short tmp[16];
    *(uint4*)tmp = d0; *(uint4*)(tmp + 8) = d1;
    #pragma unroll
    for (int e = 0; e < 16; e++) tl[row][off + e] = tmp[e];
    __syncthreads();
    int d = t >> 2, ko = (t & 3) * 16;
    unsigned short o[16];
    #pragma unroll
    for (int e = 0; e < 16; e++) o[e] = tl[ko + e][d];
    unsigned short* dst = Vt + ((size_t)bh * 64 + d) * 2048 + kt * 64 + ko;
    *(uint4*)dst = *(uint4*)o;
    *(uint4*)(dst + 8) = *(uint4*)(o + 8);
}

// ---------------- GEMM C = A @ BT^T (+bias), 128x128 tile, global_load_lds staging ----------
__global__ __launch_bounds__(256) void gemm_bt(const unsigned short* __restrict__ A,
                                               const unsigned short* __restrict__ BT,
                                               const float* __restrict__ bias,
                                               unsigned short* __restrict__ qkv_out,
                                               float* __restrict__ f32_out,
                                               int mode) {
    __shared__ alignas(16) unsigned short As[4096];   // 128 rows x 32 cols
    __shared__ alignas(16) unsigned short Bs[4096];
    const int t = threadIdx.x;
    const int wave = t >> 6, lane = t & 63, quad = lane >> 4, l16 = lane & 15;
    const int m0 = blockIdx.x * 128, n0 = blockIdx.y * 128;
    const int wm = (wave >> 1) * 64, wn = (wave & 1) * 64;
    const int r4 = lane >> 2, c16 = (lane & 3) << 4;
    const char* Ag = (const char*)A + (size_t)(m0 + wave * 32 + r4) * 2048 + c16;
    const char* Bg = (const char*)BT + (size_t)(n0 + wave * 32 + r4) * 2048 + c16;
    char* Al = (char*)As + wave * 2048;
    char* Bl = (char*)Bs + wave * 2048;
    f32x4 acc[4][4] = {};
    for (int k0 = 0; k0 < 1024; k0 += 32) {
        __syncthreads();
        gload16(Ag + k0 * 2, Al);
        gload16(Ag + k0 * 2 + 32768, Al + 1024);
        gload16(Bg + k0 * 2, Bl);
        gload16(Bg + k0 * 2 + 32768, Bl + 1024);
        __syncthreads();
        short8 af[4], bfr[4];
        #pragma unroll
        for (int i = 0; i < 4; i++)
            af[i] = *(const short8*)((const char*)As + (wm + i * 16 + l16) * 64 + (quad << 4));
        #pragma unroll
        for (int j = 0; j < 4; j++)
            bfr[j] = *(const short8*)((const char*)Bs + (wn + j * 16 + l16) * 64 + (quad << 4));
        #pragma unroll
        for (int i = 0; i < 4; i++)
            #pragma unroll
            for (int j = 0; j < 4; j++)
                acc[i][j] = MFMA16(af[i], bfr[j], acc[i][j]);
    }
    #pragma unroll
    for (int i = 0; i < 4; i++) {
        int tokb = m0 + wm + i * 16 + quad * 4;
        #pragma unroll
        for (int j = 0; j < 4; j++) {
            int n = n0 + wn + j * 16 + l16;
            float bv = bias[n];
            #pragma unroll
            for (int r = 0; r < 4; r++) {
                float v = acc[i][j][r] + bv;
                int tok = tokb + r;
                if (mode == 0) {
                    int which = n >> 10, n1 = n & 1023, h = n1 >> 6, d = n1 & 63;
                    int b = tok >> 11, s = tok & 2047;
                    qkv_out[(size_t)which * 4194304 + (((size_t)(b * 16 + h)) * 2048 + s) * 64 + d] = f2bf(v);
                } else {
                    f32_out[(size_t)tok * 1024 + n] = v;
                }
            }
        }
    }
}

// ---------------- fused attention: 8 waves, 128 q-rows/block ----------------
// grid (16,32) XCD-swizzled. Swapped QK^T (lane owns q-row = l16). m=0 softmax with
// normalization folded into the exp bias: p = exp(s*sfac + lbias), lbias = -ln(lsum).
// K/Vt tiles (64x64 bf16 = 8KB) staged via global_load_lds, double-buffered, 16B-chunk
// XOR swizzle (chunk ^= row&7) pre-applied on the GLOBAL source (linear LDS dest, rule 21).
// One K/V tile now feeds 128 q-rows -> barrier periods and staging traffic halved vs 64-row.
// Pass 2: raw s_barrier + counted vmcnt(4) so probs stores stay in flight across the barrier.
__global__ __launch_bounds__(512, 4) void attn(const unsigned short* __restrict__ Q,
                                               const unsigned short* __restrict__ K,
                                               const unsigned short* __restrict__ Vt,
                                               const int* __restrict__ amask,
                                               const int* __restrict__ stypes,
                                               const float* __restrict__ script_w,
                                               float* __restrict__ probs,
                                               unsigned short* __restrict__ ctx) {
    __shared__ alignas(16) unsigned short Ks[2][4096];    // 2 x 8KB
    __shared__ alignas(16) unsigned short Vts[2][4096];   // 2 x 8KB
    __shared__ alignas(16) unsigned short Ps[8][16][64];  // 16KB
    const int t = threadIdx.x;
    const int wave = t >> 6, lane = t & 63, quad = lane >> 4, l16 = lane & 15;
    // XCD swizzle: 512 blocks / 8 XCDs -> each XCD owns 4 complete bh (2MB K/V in its L2)
    const int bid = blockIdx.y * 16 + blockIdx.x;
    const int swz = (bid & 7) * 64 + (bid >> 3);
    const int qt = swz & 15, bh = swz >> 4;
    const int b = bh >> 4, h = bh & 15;
    const int q0 = qt * 128;
    const int qrow = q0 + wave * 16 + l16;
    const int sx16 = (l16 & 7) << 4;          // read-side XOR (bits 4-6)

    const int st = stypes[b * 2048 + qrow];
    const float sfac = script_w[st * 16 + h] * 0.125f;

    const size_t qbase = ((size_t)bh * 2048 + qrow) * 64;
    const short8 aQ0 = *(const short8*)(Q + qbase + quad * 8);
    const short8 aQ1 = *(const short8*)(Q + qbase + 32 + quad * 8);

    const char* Kg = (const char*)(K + (size_t)bh * 131072);
    const char* Vg = (const char*)(Vt + (size_t)bh * 131072);
    const int* am = amask + b * 2048;

    // staging: 512 lanes x 16B = one 8KB tile per instruction-per-wave
    const int r8 = lane >> 3;
    const int cx = ((lane & 7) ^ r8) << 4;    // pre-swizzled global chunk

#define STAGE_K(kt_, buf_) \
    gload16(Kg + (size_t)(kt_) * 8192 + (wave * 8 + r8) * 128 + cx, \
            (char*)&Ks[buf_][0] + wave * 1024)
#define STAGE_V(kt_, buf_) \
    gload16(Vg + (size_t)(wave * 8 + r8) * 4096 + (kt_) * 128 + cx, \
            (char*)&Vts[buf_][0] + wave * 1024)

    // ---- pass 1: lsum = sum_k exp(s) ----
    float lsum = 0.f;
    STAGE_K(0, 0);
    __syncthreads();
    {
        int cur = 0;
        for (int kt = 0; kt < 32; kt++) {
            if (kt < 31) STAGE_K(kt + 1, cur ^ 1);
            __builtin_amdgcn_sched_barrier(0);
            f32x4 sc[4] = {};
            const char* kbl = (const char*)&Ks[cur][0];
            #pragma unroll
            for (int j = 0; j < 4; j++) {
                const char* rp = kbl + (j * 16 + l16) * 128;
                short8 bk0 = *(const short8*)(rp + ((quad << 4) ^ sx16));
                short8 bk1 = *(const short8*)(rp + ((64 + (quad << 4)) ^ sx16));
                sc[j] = MFMA16(bk0, aQ0, sc[j]);
                sc[j] = MFMA16(bk1, aQ1, sc[j]);
            }
            #pragma unroll
            for (int j = 0; j < 4; j++) {
                int4 mi = *(const int4*)(am + kt * 64 + j * 16 + quad * 4);
                lsum += __expf(fmaf(sc[j][0], sfac, mi.x ? 0.f : NEG_INF));
                lsum += __expf(fmaf(sc[j][1], sfac, mi.y ? 0.f : NEG_INF));
                lsum += __expf(fmaf(sc[j][2], sfac, mi.z ? 0.f : NEG_INF));
                lsum += __expf(fmaf(sc[j][3], sfac, mi.w ? 0.f : NEG_INF));
            }
            __syncthreads();   // drains prefetch (hidden under this kt's compute)
            cur ^= 1;
        }
    }
    lsum += __shfl_xor(lsum, 16, 64);
    lsum += __shfl_xor(lsum, 32, 64);
    // fold 1/lsum into the exp bias: p = exp(s + lbias); all-masked row -> lbias=-inf -> p=0
    const float lbias = (lsum > 0.f) ? -__logf(lsum) : NEG_INF;

    // ---- pass 2: recompute, probs (float4), PV accumulate ----
    f32x4 oacc[4] = {};
    STAGE_K(0, 0);
    STAGE_V(0, 0);
    asm volatile("s_waitcnt vmcnt(0)" ::: "memory");
    __builtin_amdgcn_s_barrier();
    __builtin_amdgcn_sched_barrier(0);
    {
        int cur = 0;
        char* psrow = (char*)&Ps[wave][l16][0];
        for (int kt = 0; kt < 32; kt++) {
            if (kt < 31) { STAGE_K(kt + 1, cur ^ 1); STAGE_V(kt + 1, cur ^ 1); }
            __builtin_amdgcn_sched_barrier(0);   // stages are the oldest vmem ops
            f32x4 sc[4] = {};
            const char* kbl = (const char*)&Ks[cur][0];
            #pragma unroll
            for (int j = 0; j < 4; j++) {
                const char* rp = kbl + (j * 16 + l16) * 128;
                short8 bk0 = *(const short8*)(rp + ((quad << 4) ^ sx16));
                short8 bk1 = *(const short8*)(rp + ((64 + (quad << 4)) ^ sx16));
                sc[j] = MFMA16(bk0, aQ0, sc[j]);
                sc[j] = MFMA16(bk1, aQ1, sc[j]);
            }
            // preload V fragments (independent of the Ps fence below)
            short8 v0[4], v1[4];
            const char* vbl = (const char*)&Vts[cur][0];
            #pragma unroll
            for (int j2 = 0; j2 < 4; j2++) {
                const char* rp = vbl + (j2 * 16 + l16) * 128;
                v0[j2] = *(const short8*)(rp + ((quad << 4) ^ sx16));
                v1[j2] = *(const short8*)(rp + ((64 + (quad << 4)) ^ sx16));
            }
            const size_t pbase = ((size_t)bh * 2048 + qrow) * 2048 + kt * 64 + quad * 4;
            #pragma unroll
            for (int j = 0; j < 4; j++) {
                int4 mi = *(const int4*)(am + kt * 64 + j * 16 + quad * 4);
                float p0 = __expf(fmaf(sc[j][0], sfac, mi.x ? lbias : NEG_INF));
                float p1 = __expf(fmaf(sc[j][1], sfac, mi.y ? lbias : NEG_INF));
                float p2 = __expf(fmaf(sc[j][2], sfac, mi.z ? lbias : NEG_INF));
                float p3 = __expf(fmaf(sc[j][3], sfac, mi.w ? lbias : NEG_INF));
                float4 pv; pv.x = p0; pv.y = p1; pv.z = p2; pv.w = p3;
                *(float4*)(probs + pbase + j * 16) = pv;
                ushort4 pq; pq.x = f2bf(p0); pq.y = f2bf(p1); pq.z = f2bf(p2); pq.w = f2bf(p3);
                *(ushort4*)(psrow + ((j * 32 + quad * 8) ^ sx16)) = pq;
            }
            // wave-local P exchange: fence this wave's ds ops, then read A-fragments
            asm volatile("s_waitcnt lgkmcnt(0)" ::: "memory");
            __builtin_amdgcn_sched_barrier(0);
            short8 aP0 = *(const short8*)(psrow + ((quad << 4) ^ sx16));
            short8 aP1 = *(const short8*)(psrow + ((64 + (quad << 4)) ^ sx16));
            #pragma unroll
            for (int j2 = 0; j2 < 4; j2++) oacc[j2] = MFMA16(aP0, v0[j2], oacc[j2]);
            #pragma unroll
            for (int j2 = 0; j2 < 4; j2++) oacc[j2] = MFMA16(aP1, v1[j2], oacc[j2]);
            // counted wait: drains stages+masks, leaves the 4 probs stores in flight
            asm volatile("s_waitcnt vmcnt(4)" ::: "memory");
            __builtin_amdgcn_s_barrier();
            __builtin_amdgcn_sched_barrier(0);
            cur ^= 1;
        }
    }
#undef STAGE_K
#undef STAGE_V
    #pragma unroll
    for (int j2 = 0; j2 < 4; j2++)
        #pragma unroll
        for (int r = 0; r < 4; r++) {
            int qr = q0 + wave * 16 + quad * 4 + r;
            ctx[((size_t)b * 2048 + qr) * 1024 + h * 64 + j2 * 16 + l16] = f2bf(oacc[j2][r]);
        }
}

extern "C" void kernel_launch(void* const* d_in, const int* in_sizes, int n_in,
                              void* d_out, int out_size, void* d_ws, size_t ws_size,
                              hipStream_t stream) {
    const float* X    = (const float*)d_in[0];
    const int*  amask = (const int*)d_in[1];
    const int*  stp   = (const int*)d_in[2];
    const float* Wq   = (const float*)d_in[3];
    const float* bq   = (const float*)d_in[4];
    const float* Wk   = (const float*)d_in[5];
    const float* bk   = (const float*)d_in[6];
    const float* Wv   = (const float*)d_in[7];
    const float* bv   = (const float*)d_in[8];
    const float* Wo   = (const float*)d_in[9];
    const float* bo   = (const float*)d_in[10];
    const float* sw   = (const float*)d_in[11];

    float* out   = (float*)d_out;
    float* probs = out + 4194304;          // (2,16,2048,2048) fp32

    char* ws = (char*)d_ws;
    unsigned short* Xb    = (unsigned short*)(ws);               // 8 MB
    unsigned short* WqkvT = (unsigned short*)(ws + 8388608);     // 6 MB
    unsigned short* WoT   = (unsigned short*)(ws + 14680064);    // 2 MB
    float*          biasq = (float*)(ws + 16777216);             // 12 KB
    unsigned short* Qb    = (unsigned short*)(ws + 16789504);    // 8 MB  (Q,K,V contiguous)
    unsigned short* Vb    = (unsigned short*)(ws + 33566720);
    unsigned short* Vtb   = (unsigned short*)(ws + 41955328);    // 8 MB
    unsigned short* Ctx   = (unsigned short*)(ws + 50343936);    // 8 MB
    unsigned short* Kb    = Qb + 4194304;

    prep<<<8193, 256, 0, stream>>>(X, Xb, Wq, Wk, Wv, Wo, WqkvT, WoT, bq, bk, bv, biasq);
    gemm_bt<<<dim3(32, 24), 256, 0, stream>>>(Xb, WqkvT, biasq, Qb, nullptr, 0);
    transpose_v<<<1024, 256, 0, stream>>>(Vb, Vtb);
    attn<<<dim3(16, 32), 512, 0, stream>>>(Qb, Kb, Vtb, amask, stp, sw, probs, Ctx);
    gemm_bt<<<dim3(32, 8), 256, 0, stream>>>(Ctx, WoT, bo, nullptr, out, 1);
}

// Round 6
// 296.692 us; speedup vs baseline: 1.0249x; 1.0249x over previous
//
#include <hip/hip_runtime.h>
#include <hip/hip_bf16.h>
#include <cstdint>
#include <cstddef>

typedef __attribute__((ext_vector_type(8))) short short8;
typedef __attribute__((ext_vector_type(4))) float f32x4;

#define MFMA16(a,b,c) __builtin_amdgcn_mfma_f32_16x16x32_bf16((a),(b),(c),0,0,0)
#define NEG_INF (-__builtin_inff())

__device__ __forceinline__ unsigned short f2bf(float f) {
    union { float f; unsigned int u; } a; a.f = f;
    return (unsigned short)((a.u + 0x7FFFu + ((a.u >> 16) & 1u)) >> 16);
}

// async global->LDS, 16B per lane. LDS dest = uniform base + lane*16.
__device__ __forceinline__ void gload16(const void* g, void* l) {
    __builtin_amdgcn_global_load_lds(
        (const __attribute__((address_space(1))) void*)g,
        (__attribute__((address_space(3))) void*)l, 16, 0, 0);
}

// ---------------- fused prep: X->bf16, 4x W-transpose, bias pack ----------------
__global__ __launch_bounds__(256) void prep(const float* __restrict__ X,
                                            unsigned short* __restrict__ Xb,
                                            const float* __restrict__ Wq,
                                            const float* __restrict__ Wk,
                                            const float* __restrict__ Wv,
                                            const float* __restrict__ Wo,
                                            unsigned short* __restrict__ WqkvT,
                                            unsigned short* __restrict__ WoT,
                                            const float* __restrict__ bq,
                                            const float* __restrict__ bk,
                                            const float* __restrict__ bv,
                                            float* __restrict__ biasq) {
    const int bid = blockIdx.x;
    const int t = threadIdx.x;
    if (bid < 4096) {
        int i = (bid * 256 + t) * 4;
        float4 v = *(const float4*)(X + i);
        ushort4 o;
        o.x = f2bf(v.x); o.y = f2bf(v.y); o.z = f2bf(v.z); o.w = f2bf(v.w);
        *(ushort4*)(Xb + i) = o;
    } else if (bid < 8192) {
        __shared__ float tile[32][33];
        const int wid = bid - 4096;
        const int which = wid >> 10, t32 = wid & 1023;
        const float* W = (which == 0) ? Wq : (which == 1) ? Wk : (which == 2) ? Wv : Wo;
        unsigned short* WT = (which < 3) ? (WqkvT + which * 1048576) : WoT;
        int tx = t & 31, ty = t >> 5;
        int kb = (t32 & 31) * 32, nb = (t32 >> 5) * 32;
        #pragma unroll
        for (int r = 0; r < 32; r += 8)
            tile[ty + r][tx] = W[(size_t)(kb + ty + r) * 1024 + nb + tx];
        __syncthreads();
        #pragma unroll
        for (int r = 0; r < 32; r += 8) {
            float v = tile[tx][ty + r];
            WT[(size_t)(nb + ty + r) * 1024 + kb + tx] = f2bf(v);
        }
    } else {
        for (int i = t; i < 3072; i += 256) {
            const float* s = (i < 1024) ? bq : (i < 2048) ? bk : bv;
            biasq[i] = s[i & 1023];
        }
    }
}

// ---------------- QKV GEMM: C = X @ WqkvT^T (+bias), 128x128 tile ----------------
// Q,K -> packed [2][B,H,S,64] bf16 (scalar stores); V -> written TRANSPOSED into
// Vt [B*H][64][2048] via ushort4 stores (s = r-loop is contiguous), killing transpose_v.
__global__ __launch_bounds__(256) void gemm_qkv(const unsigned short* __restrict__ A,
                                                const unsigned short* __restrict__ BT,
                                                const float* __restrict__ bias,
                                                unsigned short* __restrict__ qk_out,
                                                unsigned short* __restrict__ vt_out) {
    __shared__ alignas(16) unsigned short As[4096];   // 128 rows x 32 cols
    __shared__ alignas(16) unsigned short Bs[4096];
    const int t = threadIdx.x;
    const int wave = t >> 6, lane = t & 63, quad = lane >> 4, l16 = lane & 15;
    const int m0 = blockIdx.x * 128, n0 = blockIdx.y * 128;
    const int wm = (wave >> 1) * 64, wn = (wave & 1) * 64;
    const int r4 = lane >> 2, c16 = (lane & 3) << 4;
    const char* Ag = (const char*)A + (size_t)(m0 + wave * 32 + r4) * 2048 + c16;
    const char* Bg = (const char*)BT + (size_t)(n0 + wave * 32 + r4) * 2048 + c16;
    char* Al = (char*)As + wave * 2048;
    char* Bl = (char*)Bs + wave * 2048;
    f32x4 acc[4][4] = {};
    for (int k0 = 0; k0 < 1024; k0 += 32) {
        __syncthreads();
        gload16(Ag + k0 * 2, Al);
        gload16(Ag + k0 * 2 + 32768, Al + 1024);
        gload16(Bg + k0 * 2, Bl);
        gload16(Bg + k0 * 2 + 32768, Bl + 1024);
        __syncthreads();
        short8 af[4], bfr[4];
        #pragma unroll
        for (int i = 0; i < 4; i++)
            af[i] = *(const short8*)((const char*)As + (wm + i * 16 + l16) * 64 + (quad << 4));
        #pragma unroll
        for (int j = 0; j < 4; j++)
            bfr[j] = *(const short8*)((const char*)Bs + (wn + j * 16 + l16) * 64 + (quad << 4));
        #pragma unroll
        for (int i = 0; i < 4; i++)
            #pragma unroll
            for (int j = 0; j < 4; j++)
                acc[i][j] = MFMA16(af[i], bfr[j], acc[i][j]);
    }
    #pragma unroll
    for (int i = 0; i < 4; i++) {
        int tokb = m0 + wm + i * 16 + quad * 4;
        int b = tokb >> 11, s = tokb & 2047;
        #pragma unroll
        for (int j = 0; j < 4; j++) {
            int n = n0 + wn + j * 16 + l16;
            float bv = bias[n];
            int which = n >> 10, n1 = n & 1023, h = n1 >> 6, d = n1 & 63;
            if (which == 2) {
                // V: transposed write, s contiguous -> one ushort4
                ushort4 pv;
                pv.x = f2bf(acc[i][j][0] + bv);
                pv.y = f2bf(acc[i][j][1] + bv);
                pv.z = f2bf(acc[i][j][2] + bv);
                pv.w = f2bf(acc[i][j][3] + bv);
                *(ushort4*)(vt_out + ((size_t)(b * 16 + h) * 64 + d) * 2048 + s) = pv;
            } else {
                #pragma unroll
                for (int r = 0; r < 4; r++) {
                    float v = acc[i][j][r] + bv;
                    qk_out[(size_t)which * 4194304 +
                           (((size_t)(b * 16 + h)) * 2048 + s + r) * 64 + d] = f2bf(v);
                }
            }
        }
    }
}

// ---------------- out-proj GEMM: 64x128 tile (512 blocks = 2/CU) ----------------
__global__ __launch_bounds__(256) void gemm_out(const unsigned short* __restrict__ A,
                                                const unsigned short* __restrict__ BT,
                                                const float* __restrict__ bias,
                                                float* __restrict__ C) {
    __shared__ alignas(16) unsigned short As[2048];   // 64 rows x 32 cols
    __shared__ alignas(16) unsigned short Bs[4096];   // 128 rows x 32 cols
    const int t = threadIdx.x;
    const int wave = t >> 6, lane = t & 63, quad = lane >> 4, l16 = lane & 15;
    const int m0 = blockIdx.x * 64, n0 = blockIdx.y * 128;
    const int wm = (wave >> 1) * 32, wn = (wave & 1) * 64;
    const int r4 = lane >> 2, c16 = (lane & 3) << 4;
    const char* Ag = (const char*)A + (size_t)(m0 + wave * 16 + r4) * 2048 + c16;
    const char* Bg = (const char*)BT + (size_t)(n0 + wave * 32 + r4) * 2048 + c16;
    char* Al = (char*)As + wave * 1024;
    char* Bl = (char*)Bs + wave * 2048;
    f32x4 acc[2][4] = {};
    for (int k0 = 0; k0 < 1024; k0 += 32) {
        __syncthreads();
        gload16(Ag + k0 * 2, Al);
        gload16(Bg + k0 * 2, Bl);
        gload16(Bg + k0 * 2 + 32768, Bl + 1024);
        __syncthreads();
        short8 af[2], bfr[4];
        #pragma unroll
        for (int i = 0; i < 2; i++)
            af[i] = *(const short8*)((const char*)As + (wm + i * 16 + l16) * 64 + (quad << 4));
        #pragma unroll
        for (int j = 0; j < 4; j++)
            bfr[j] = *(const short8*)((const char*)Bs + (wn + j * 16 + l16) * 64 + (quad << 4));
        #pragma unroll
        for (int i = 0; i < 2; i++)
            #pragma unroll
            for (int j = 0; j < 4; j++)
                acc[i][j] = MFMA16(af[i], bfr[j], acc[i][j]);
    }
    #pragma unroll
    for (int i = 0; i < 2; i++) {
        int tokb = m0 + wm + i * 16 + quad * 4;
        #pragma unroll
        for (int j = 0; j < 4; j++) {
            int n = n0 + wn + j * 16 + l16;
            float bv = bias[n];
            #pragma unroll
            for (int r = 0; r < 4; r++)
                C[(size_t)(tokb + r) * 1024 + n] = acc[i][j][r] + bv;
        }
    }
}

// ---------------- fused attention: 8 waves, 128 q-rows/block ----------------
// Swapped QK^T (lane owns q-row = l16), m=0 softmax with normalization folded into exp
// bias. K/Vt tiles staged via global_load_lds (pre-swizzled source, rule 21), double-
// buffered. probs stores are NONTEMPORAL (write-once stream; keep K/V in L2).
// setprio(1) wraps the MFMA clusters (T5). Pass-2 barrier = counted vmcnt + s_barrier.
__global__ __launch_bounds__(512, 4) void attn(const unsigned short* __restrict__ Q,
                                               const unsigned short* __restrict__ K,
                                               const unsigned short* __restrict__ Vt,
                                               const int* __restrict__ amask,
                                               const int* __restrict__ stypes,
                                               const float* __restrict__ script_w,
                                               float* __restrict__ probs,
                                               unsigned short* __restrict__ ctx) {
    __shared__ alignas(16) unsigned short Ks[2][4096];    // 2 x 8KB
    __shared__ alignas(16) unsigned short Vts[2][4096];   // 2 x 8KB
    __shared__ alignas(16) unsigned short Ps[8][16][64];  // 16KB
    const int t = threadIdx.x;
    const int wave = t >> 6, lane = t & 63, quad = lane >> 4, l16 = lane & 15;
    const int bid = blockIdx.y * 16 + blockIdx.x;
    const int swz = (bid & 7) * 64 + (bid >> 3);
    const int qt = swz & 15, bh = swz >> 4;
    const int b = bh >> 4, h = bh & 15;
    const int q0 = qt * 128;
    const int qrow = q0 + wave * 16 + l16;
    const int sx16 = (l16 & 7) << 4;

    const int st = stypes[b * 2048 + qrow];
    const float sfac = script_w[st * 16 + h] * 0.125f;

    const size_t qbase = ((size_t)bh * 2048 + qrow) * 64;
    const short8 aQ0 = *(const short8*)(Q + qbase + quad * 8);
    const short8 aQ1 = *(const short8*)(Q + qbase + 32 + quad * 8);

    const char* Kg = (const char*)(K + (size_t)bh * 131072);
    const char* Vg = (const char*)(Vt + (size_t)bh * 131072);
    const int* am = amask + b * 2048;

    const int r8 = lane >> 3;
    const int cx = ((lane & 7) ^ r8) << 4;    // pre-swizzled global chunk

#define STAGE_K(kt_, buf_) \
    gload16(Kg + (size_t)(kt_) * 8192 + (wave * 8 + r8) * 128 + cx, \
            (char*)&Ks[buf_][0] + wave * 1024)
#define STAGE_V(kt_, buf_) \
    gload16(Vg + (size_t)(wave * 8 + r8) * 4096 + (kt_) * 128 + cx, \
            (char*)&Vts[buf_][0] + wave * 1024)

    // ---- pass 1: lsum = sum_k exp(s) ----
    float lsum = 0.f;
    STAGE_K(0, 0);
    __syncthreads();
    {
        int cur = 0;
        for (int kt = 0; kt < 32; kt++) {
            if (kt < 31) STAGE_K(kt + 1, cur ^ 1);
            __builtin_amdgcn_sched_barrier(0);
            f32x4 sc[4] = {};
            const char* kbl = (const char*)&Ks[cur][0];
            __builtin_amdgcn_s_setprio(1);
            #pragma unroll
            for (int j = 0; j < 4; j++) {
                const char* rp = kbl + (j * 16 + l16) * 128;
                short8 bk0 = *(const short8*)(rp + ((quad << 4) ^ sx16));
                short8 bk1 = *(const short8*)(rp + ((64 + (quad << 4)) ^ sx16));
                sc[j] = MFMA16(bk0, aQ0, sc[j]);
                sc[j] = MFMA16(bk1, aQ1, sc[j]);
            }
            __builtin_amdgcn_s_setprio(0);
            #pragma unroll
            for (int j = 0; j < 4; j++) {
                int4 mi = *(const int4*)(am + kt * 64 + j * 16 + quad * 4);
                lsum += __expf(fmaf(sc[j][0], sfac, mi.x ? 0.f : NEG_INF));
                lsum += __expf(fmaf(sc[j][1], sfac, mi.y ? 0.f : NEG_INF));
                lsum += __expf(fmaf(sc[j][2], sfac, mi.z ? 0.f : NEG_INF));
                lsum += __expf(fmaf(sc[j][3], sfac, mi.w ? 0.f : NEG_INF));
            }
            __syncthreads();
            cur ^= 1;
        }
    }
    lsum += __shfl_xor(lsum, 16, 64);
    lsum += __shfl_xor(lsum, 32, 64);
    const float lbias = (lsum > 0.f) ? -__logf(lsum) : NEG_INF;

    // ---- pass 2: recompute, probs (nontemporal f32x4), PV accumulate ----
    f32x4 oacc[4] = {};
    STAGE_K(0, 0);
    STAGE_V(0, 0);
    asm volatile("s_waitcnt vmcnt(0)" ::: "memory");
    __builtin_amdgcn_s_barrier();
    __builtin_amdgcn_sched_barrier(0);
    {
        int cur = 0;
        char* psrow = (char*)&Ps[wave][l16][0];
        for (int kt = 0; kt < 32; kt++) {
            if (kt < 31) { STAGE_K(kt + 1, cur ^ 1); STAGE_V(kt + 1, cur ^ 1); }
            __builtin_amdgcn_sched_barrier(0);
            f32x4 sc[4] = {};
            const char* kbl = (const char*)&Ks[cur][0];
            __builtin_amdgcn_s_setprio(1);
            #pragma unroll
            for (int j = 0; j < 4; j++) {
                const char* rp = kbl + (j * 16 + l16) * 128;
                short8 bk0 = *(const short8*)(rp + ((quad << 4) ^ sx16));
                short8 bk1 = *(const short8*)(rp + ((64 + (quad << 4)) ^ sx16));
                sc[j] = MFMA16(bk0, aQ0, sc[j]);
                sc[j] = MFMA16(bk1, aQ1, sc[j]);
            }
            __builtin_amdgcn_s_setprio(0);
            // preload V fragments (independent of the Ps fence below)
            short8 v0[4], v1[4];
            const char* vbl = (const char*)&Vts[cur][0];
            #pragma unroll
            for (int j2 = 0; j2 < 4; j2++) {
                const char* rp = vbl + (j2 * 16 + l16) * 128;
                v0[j2] = *(const short8*)(rp + ((quad << 4) ^ sx16));
                v1[j2] = *(const short8*)(rp + ((64 + (quad << 4)) ^ sx16));
            }
            const size_t pbase = ((size_t)bh * 2048 + qrow) * 2048 + kt * 64 + quad * 4;
            #pragma unroll
            for (int j = 0; j < 4; j++) {
                int4 mi = *(const int4*)(am + kt * 64 + j * 16 + quad * 4);
                float p0 = __expf(fmaf(sc[j][0], sfac, mi.x ? lbias : NEG_INF));
                float p1 = __expf(fmaf(sc[j][1], sfac, mi.y ? lbias : NEG_INF));
                float p2 = __expf(fmaf(sc[j][2], sfac, mi.z ? lbias : NEG_INF));
                float p3 = __expf(fmaf(sc[j][3], sfac, mi.w ? lbias : NEG_INF));
                f32x4 pv; pv[0] = p0; pv[1] = p1; pv[2] = p2; pv[3] = p3;
                __builtin_nontemporal_store(pv, (f32x4*)(probs + pbase + j * 16));
                ushort4 pq; pq.x = f2bf(p0); pq.y = f2bf(p1); pq.z = f2bf(p2); pq.w = f2bf(p3);
                *(ushort4*)(psrow + ((j * 32 + quad * 8) ^ sx16)) = pq;
            }
            // wave-local P exchange: fence this wave's ds ops, then read A-fragments
            asm volatile("s_waitcnt lgkmcnt(0)" ::: "memory");
            __builtin_amdgcn_sched_barrier(0);
            short8 aP0 = *(const short8*)(psrow + ((quad << 4) ^ sx16));
            short8 aP1 = *(const short8*)(psrow + ((64 + (quad << 4)) ^ sx16));
            __builtin_amdgcn_s_setprio(1);
            #pragma unroll
            for (int j2 = 0; j2 < 4; j2++) oacc[j2] = MFMA16(aP0, v0[j2], oacc[j2]);
            #pragma unroll
            for (int j2 = 0; j2 < 4; j2++) oacc[j2] = MFMA16(aP1, v1[j2], oacc[j2]);
            __builtin_amdgcn_s_setprio(0);
            // counted wait: drains stages, leaves probs stores in flight
            asm volatile("s_waitcnt vmcnt(4)" ::: "memory");
            __builtin_amdgcn_s_barrier();
            __builtin_amdgcn_sched_barrier(0);
            cur ^= 1;
        }
    }
#undef STAGE_K
#undef STAGE_V
    #pragma unroll
    for (int j2 = 0; j2 < 4; j2++)
        #pragma unroll
        for (int r = 0; r < 4; r++) {
            int qr = q0 + wave * 16 + quad * 4 + r;
            ctx[((size_t)b * 2048 + qr) * 1024 + h * 64 + j2 * 16 + l16] = f2bf(oacc[j2][r]);
        }
}

extern "C" void kernel_launch(void* const* d_in, const int* in_sizes, int n_in,
                              void* d_out, int out_size, void* d_ws, size_t ws_size,
                              hipStream_t stream) {
    const float* X    = (const float*)d_in[0];
    const int*  amask = (const int*)d_in[1];
    const int*  stp   = (const int*)d_in[2];
    const float* Wq   = (const float*)d_in[3];
    const float* bq   = (const float*)d_in[4];
    const float* Wk   = (const float*)d_in[5];
    const float* bk   = (const float*)d_in[6];
    const float* Wv   = (const float*)d_in[7];
    const float* bv   = (const float*)d_in[8];
    const float* Wo   = (const float*)d_in[9];
    const float* bo   = (const float*)d_in[10];
    const float* sw   = (const float*)d_in[11];

    float* out   = (float*)d_out;
    float* probs = out + 4194304;          // (2,16,2048,2048) fp32

    char* ws = (char*)d_ws;
    unsigned short* Xb    = (unsigned short*)(ws);               // 8 MB
    unsigned short* WqkvT = (unsigned short*)(ws + 8388608);     // 6 MB
    unsigned short* WoT   = (unsigned short*)(ws + 14680064);    // 2 MB
    float*          biasq = (float*)(ws + 16777216);             // 12 KB
    unsigned short* Qb    = (unsigned short*)(ws + 16789504);    // 8 MB (Q,K contiguous)
    unsigned short* Vtb   = (unsigned short*)(ws + 41955328);    // 8 MB (V^T, written by gemm_qkv)
    unsigned short* Ctx   = (unsigned short*)(ws + 50343936);    // 8 MB
    unsigned short* Kb    = Qb + 4194304;

    prep<<<8193, 256, 0, stream>>>(X, Xb, Wq, Wk, Wv, Wo, WqkvT, WoT, bq, bk, bv, biasq);
    gemm_qkv<<<dim3(32, 24), 256, 0, stream>>>(Xb, WqkvT, biasq, Qb, Vtb);
    attn<<<dim3(16, 32), 512, 0, stream>>>(Qb, Kb, Vtb, amask, stp, sw, probs, Ctx);
    gemm_out<<<dim3(64, 8), 256, 0, stream>>>(Ctx, WoT, bo, out);
}

// Round 7
// 288.177 us; speedup vs baseline: 1.0552x; 1.0295x over previous
//
#include <hip/hip_runtime.h>
#include <hip/hip_bf16.h>
#include <cstdint>
#include <cstddef>

typedef __attribute__((ext_vector_type(8))) short short8;
typedef __attribute__((ext_vector_type(4))) float f32x4;

#define MFMA16(a,b,c) __builtin_amdgcn_mfma_f32_16x16x32_bf16((a),(b),(c),0,0,0)
#define NEG_INF (-__builtin_inff())

__device__ __forceinline__ unsigned short f2bf(float f) {
    union { float f; unsigned int u; } a; a.f = f;
    return (unsigned short)((a.u + 0x7FFFu + ((a.u >> 16) & 1u)) >> 16);
}

// pack 2 f32 -> 2 bf16 (RNE) in one instruction (T12 primitive; no builtin on gfx950)
__device__ __forceinline__ unsigned int cvtpk_bf16(float a, float b) {
    unsigned int r;
    asm("v_cvt_pk_bf16_f32 %0, %1, %2" : "=v"(r) : "v"(a), "v"(b));
    return r;
}

// async global->LDS, 16B per lane. LDS dest = uniform base + lane*16.
__device__ __forceinline__ void gload16(const void* g, void* l) {
    __builtin_amdgcn_global_load_lds(
        (const __attribute__((address_space(1))) void*)g,
        (__attribute__((address_space(3))) void*)l, 16, 0, 0);
}

// ---------------- fused prep: X->bf16, 4x W-transpose, bias pack ----------------
__global__ __launch_bounds__(256) void prep(const float* __restrict__ X,
                                            unsigned short* __restrict__ Xb,
                                            const float* __restrict__ Wq,
                                            const float* __restrict__ Wk,
                                            const float* __restrict__ Wv,
                                            const float* __restrict__ Wo,
                                            unsigned short* __restrict__ WqkvT,
                                            unsigned short* __restrict__ WoT,
                                            const float* __restrict__ bq,
                                            const float* __restrict__ bk,
                                            const float* __restrict__ bv,
                                            float* __restrict__ biasq) {
    const int bid = blockIdx.x;
    const int t = threadIdx.x;
    if (bid < 4096) {
        int i = (bid * 256 + t) * 4;
        float4 v = *(const float4*)(X + i);
        ushort4 o;
        o.x = f2bf(v.x); o.y = f2bf(v.y); o.z = f2bf(v.z); o.w = f2bf(v.w);
        *(ushort4*)(Xb + i) = o;
    } else if (bid < 8192) {
        __shared__ float tile[32][33];
        const int wid = bid - 4096;
        const int which = wid >> 10, t32 = wid & 1023;
        const float* W = (which == 0) ? Wq : (which == 1) ? Wk : (which == 2) ? Wv : Wo;
        unsigned short* WT = (which < 3) ? (WqkvT + which * 1048576) : WoT;
        int tx = t & 31, ty = t >> 5;
        int kb = (t32 & 31) * 32, nb = (t32 >> 5) * 32;
        #pragma unroll
        for (int r = 0; r < 32; r += 8)
            tile[ty + r][tx] = W[(size_t)(kb + ty + r) * 1024 + nb + tx];
        __syncthreads();
        #pragma unroll
        for (int r = 0; r < 32; r += 8) {
            float v = tile[tx][ty + r];
            WT[(size_t)(nb + ty + r) * 1024 + kb + tx] = f2bf(v);
        }
    } else {
        for (int i = t; i < 3072; i += 256) {
            const float* s = (i < 1024) ? bq : (i < 2048) ? bk : bv;
            biasq[i] = s[i & 1023];
        }
    }
}

// ---------------- QKV GEMM: C = X @ WqkvT^T (+bias), 128x128 tile ----------------
// Q,K -> packed [2][B,H,S,64] bf16; V -> written TRANSPOSED into Vt [B*H][64][2048].
__global__ __launch_bounds__(256) void gemm_qkv(const unsigned short* __restrict__ A,
                                                const unsigned short* __restrict__ BT,
                                                const float* __restrict__ bias,
                                                unsigned short* __restrict__ qk_out,
                                                unsigned short* __restrict__ vt_out) {
    __shared__ alignas(16) unsigned short As[4096];   // 128 rows x 32 cols
    __shared__ alignas(16) unsigned short Bs[4096];
    const int t = threadIdx.x;
    const int wave = t >> 6, lane = t & 63, quad = lane >> 4, l16 = lane & 15;
    const int m0 = blockIdx.x * 128, n0 = blockIdx.y * 128;
    const int wm = (wave >> 1) * 64, wn = (wave & 1) * 64;
    const int r4 = lane >> 2, c16 = (lane & 3) << 4;
    const char* Ag = (const char*)A + (size_t)(m0 + wave * 32 + r4) * 2048 + c16;
    const char* Bg = (const char*)BT + (size_t)(n0 + wave * 32 + r4) * 2048 + c16;
    char* Al = (char*)As + wave * 2048;
    char* Bl = (char*)Bs + wave * 2048;
    f32x4 acc[4][4] = {};
    for (int k0 = 0; k0 < 1024; k0 += 32) {
        __syncthreads();
        gload16(Ag + k0 * 2, Al);
        gload16(Ag + k0 * 2 + 32768, Al + 1024);
        gload16(Bg + k0 * 2, Bl);
        gload16(Bg + k0 * 2 + 32768, Bl + 1024);
        __syncthreads();
        short8 af[4], bfr[4];
        #pragma unroll
        for (int i = 0; i < 4; i++)
            af[i] = *(const short8*)((const char*)As + (wm + i * 16 + l16) * 64 + (quad << 4));
        #pragma unroll
        for (int j = 0; j < 4; j++)
            bfr[j] = *(const short8*)((const char*)Bs + (wn + j * 16 + l16) * 64 + (quad << 4));
        #pragma unroll
        for (int i = 0; i < 4; i++)
            #pragma unroll
            for (int j = 0; j < 4; j++)
                acc[i][j] = MFMA16(af[i], bfr[j], acc[i][j]);
    }
    #pragma unroll
    for (int i = 0; i < 4; i++) {
        int tokb = m0 + wm + i * 16 + quad * 4;
        int b = tokb >> 11, s = tokb & 2047;
        #pragma unroll
        for (int j = 0; j < 4; j++) {
            int n = n0 + wn + j * 16 + l16;
            float bv = bias[n];
            int which = n >> 10, n1 = n & 1023, h = n1 >> 6, d = n1 & 63;
            if (which == 2) {
                ushort4 pv;
                pv.x = f2bf(acc[i][j][0] + bv);
                pv.y = f2bf(acc[i][j][1] + bv);
                pv.z = f2bf(acc[i][j][2] + bv);
                pv.w = f2bf(acc[i][j][3] + bv);
                *(ushort4*)(vt_out + ((size_t)(b * 16 + h) * 64 + d) * 2048 + s) = pv;
            } else {
                #pragma unroll
                for (int r = 0; r < 4; r++) {
                    float v = acc[i][j][r] + bv;
                    qk_out[(size_t)which * 4194304 +
                           (((size_t)(b * 16 + h)) * 2048 + s + r) * 64 + d] = f2bf(v);
                }
            }
        }
    }
}

// ---------------- out-proj GEMM: 64x128 tile (512 blocks = 2/CU) ----------------
__global__ __launch_bounds__(256) void gemm_out(const unsigned short* __restrict__ A,
                                                const unsigned short* __restrict__ BT,
                                                const float* __restrict__ bias,
                                                float* __restrict__ C) {
    __shared__ alignas(16) unsigned short As[2048];
    __shared__ alignas(16) unsigned short Bs[4096];
    const int t = threadIdx.x;
    const int wave = t >> 6, lane = t & 63, quad = lane >> 4, l16 = lane & 15;
    const int m0 = blockIdx.x * 64, n0 = blockIdx.y * 128;
    const int wm = (wave >> 1) * 32, wn = (wave & 1) * 64;
    const int r4 = lane >> 2, c16 = (lane & 3) << 4;
    const char* Ag = (const char*)A + (size_t)(m0 + wave * 16 + r4) * 2048 + c16;
    const char* Bg = (const char*)BT + (size_t)(n0 + wave * 32 + r4) * 2048 + c16;
    char* Al = (char*)As + wave * 1024;
    char* Bl = (char*)Bs + wave * 2048;
    f32x4 acc[2][4] = {};
    for (int k0 = 0; k0 < 1024; k0 += 32) {
        __syncthreads();
        gload16(Ag + k0 * 2, Al);
        gload16(Bg + k0 * 2, Bl);
        gload16(Bg + k0 * 2 + 32768, Bl + 1024);
        __syncthreads();
        short8 af[2], bfr[4];
        #pragma unroll
        for (int i = 0; i < 2; i++)
            af[i] = *(const short8*)((const char*)As + (wm + i * 16 + l16) * 64 + (quad << 4));
        #pragma unroll
        for (int j = 0; j < 4; j++)
            bfr[j] = *(const short8*)((const char*)Bs + (wn + j * 16 + l16) * 64 + (quad << 4));
        #pragma unroll
        for (int i = 0; i < 2; i++)
            #pragma unroll
            for (int j = 0; j < 4; j++)
                acc[i][j] = MFMA16(af[i], bfr[j], acc[i][j]);
    }
    #pragma unroll
    for (int i = 0; i < 2; i++) {
        int tokb = m0 + wm + i * 16 + quad * 4;
        #pragma unroll
        for (int j = 0; j < 4; j++) {
            int n = n0 + wn + j * 16 + l16;
            float bv = bias[n];
            #pragma unroll
            for (int r = 0; r < 4; r++)
                C[(size_t)(tokb + r) * 1024 + n] = acc[i][j][r] + bv;
        }
    }
}

// ---------------- fused attention: 8 waves, 128 q-rows, cross-kt pipeline ----------------
// Software pipeline: exp/probs/Ps(kt) [VALU+stores] co-scheduled with QK^T(kt+1)
// [MFMA + LDS] in one region; 3-buffer K/V rotation; stages issued under if(kt<30)
// (branch pins issue order -> counted vmcnt(4) leaves only this iter's probs stores
// in flight). Mask bias in LDS (mb), Ps packing via v_cvt_pk_bf16_f32.
__global__ __launch_bounds__(512, 4) void attn(const unsigned short* __restrict__ Q,
                                               const unsigned short* __restrict__ K,
                                               const unsigned short* __restrict__ Vt,
                                               const int* __restrict__ amask,
                                               const int* __restrict__ stypes,
                                               const float* __restrict__ script_w,
                                               float* __restrict__ probs,
                                               unsigned short* __restrict__ ctx) {
    __shared__ alignas(16) unsigned short KsA[3][4096];   // 3 x 8KB rotating
    __shared__ alignas(16) unsigned short VtsA[3][4096];  // 3 x 8KB rotating
    __shared__ alignas(16) unsigned short Ps[8][16][64];  // 16KB
    __shared__ alignas(16) float mb[2048];                // 8KB mask bias
    const int t = threadIdx.x;
    const int wave = t >> 6, lane = t & 63, quad = lane >> 4, l16 = lane & 15;
    const int bid = blockIdx.y * 16 + blockIdx.x;
    const int swz = (bid & 7) * 64 + (bid >> 3);
    const int qt = swz & 15, bh = swz >> 4;
    const int b = bh >> 4, h = bh & 15;
    const int q0 = qt * 128;
    const int qrow = q0 + wave * 16 + l16;
    const int sx16 = (l16 & 7) << 4;

    const int st = stypes[b * 2048 + qrow];
    const float sfac = script_w[st * 16 + h] * 0.125f;

    const size_t qbase = ((size_t)bh * 2048 + qrow) * 64;
    const short8 aQ0 = *(const short8*)(Q + qbase + quad * 8);
    const short8 aQ1 = *(const short8*)(Q + qbase + 32 + quad * 8);

    const char* Kg = (const char*)(K + (size_t)bh * 131072);
    const char* Vg = (const char*)(Vt + (size_t)bh * 131072);

    {   // mask -> bias table in LDS: mb[k] = mask[k] ? 0 : -inf  (once per block)
        int4 m4 = *(const int4*)(amask + b * 2048 + t * 4);
        f32x4 mv;
        mv[0] = m4.x ? 0.f : NEG_INF;
        mv[1] = m4.y ? 0.f : NEG_INF;
        mv[2] = m4.z ? 0.f : NEG_INF;
        mv[3] = m4.w ? 0.f : NEG_INF;
        *(f32x4*)&mb[t * 4] = mv;
    }

    const int r8 = lane >> 3;
    const int cx = ((lane & 7) ^ r8) << 4;    // pre-swizzled global chunk (rule 21)
    char* KsB = (char*)&KsA[0][0];
    char* VtsB = (char*)&VtsA[0][0];

#define STAGE_K(kt_, ob_) \
    gload16(Kg + (size_t)(kt_) * 8192 + (wave * 8 + r8) * 128 + cx, KsB + (ob_) + wave * 1024)
#define STAGE_V(kt_, ob_) \
    gload16(Vg + (size_t)(wave * 8 + r8) * 4096 + (kt_) * 128 + cx, VtsB + (ob_) + wave * 1024)
#define QKT(dst_, ob_) do { \
        const char* _kb = KsB + (ob_); \
        _Pragma("unroll") \
        for (int _j = 0; _j < 4; _j++) { \
            const char* _rp = _kb + (_j * 16 + l16) * 128; \
            short8 _k0 = *(const short8*)(_rp + ((quad << 4) ^ sx16)); \
            short8 _k1 = *(const short8*)(_rp + ((64 + (quad << 4)) ^ sx16)); \
            dst_[_j] = MFMA16(_k0, aQ0, dst_[_j]); \
            dst_[_j] = MFMA16(_k1, aQ1, dst_[_j]); \
        } } while (0)

    int ob0 = 0, ob1 = 8192, ob2 = 16384;

    // ---- pass 1: lsum = sum_k exp(s), pipelined (sum(kt) || QK^T(kt+1)) ----
    float lsum = 0.f;
    STAGE_K(0, ob0);
    STAGE_K(1, ob1);
    __syncthreads();
    f32x4 sc[4] = {};
    QKT(sc, ob0);
    for (int kt = 0; kt < 32; kt++) {
        if (kt < 30) STAGE_K(kt + 2, ob2);
        #pragma unroll
        for (int j = 0; j < 4; j++) {
            f32x4 mv = *(const f32x4*)&mb[kt * 64 + j * 16 + quad * 4];
            float e0 = __expf(fmaf(sc[j][0], sfac, mv[0]));
            float e1 = __expf(fmaf(sc[j][1], sfac, mv[1]));
            float e2 = __expf(fmaf(sc[j][2], sfac, mv[2]));
            float e3 = __expf(fmaf(sc[j][3], sfac, mv[3]));
            lsum += (e0 + e1) + (e2 + e3);
        }
        f32x4 scn[4] = {};
        if (kt < 31) QKT(scn, ob1);
        __syncthreads();          // drains stage (1-iter window) + buffer-rotation safety
        int tmp = ob0; ob0 = ob1; ob1 = ob2; ob2 = tmp;
        #pragma unroll
        for (int j = 0; j < 4; j++) sc[j] = scn[j];
    }
    lsum += __shfl_xor(lsum, 16, 64);
    lsum += __shfl_xor(lsum, 32, 64);
    const float inv_l = (lsum > 0.f) ? 1.0f / lsum : 0.0f;

    // ---- pass 2: probs + PV, pipelined ----
    f32x4 oacc[4] = {};
    ob0 = 0; ob1 = 8192; ob2 = 16384;
    STAGE_K(0, ob0); STAGE_V(0, ob0);
    STAGE_K(1, ob1); STAGE_V(1, ob1);
    __syncthreads();
    f32x4 sc2[4] = {};
    QKT(sc2, ob0);
    char* psrow = (char*)&Ps[wave][l16][0];
    for (int kt = 0; kt < 32; kt++) {
        if (kt < 30) { STAGE_K(kt + 2, ob2); STAGE_V(kt + 2, ob2); }
        // --- region A: softmax(kt) + probs stores + Ps writes  ||  QK^T(kt+1) ---
        const size_t pbase = ((size_t)bh * 2048 + qrow) * 2048 + kt * 64 + quad * 4;
        #pragma unroll
        for (int j = 0; j < 4; j++) {
            f32x4 mv = *(const f32x4*)&mb[kt * 64 + j * 16 + quad * 4];
            float p0 = __expf(fmaf(sc2[j][0], sfac, mv[0])) * inv_l;
            float p1 = __expf(fmaf(sc2[j][1], sfac, mv[1])) * inv_l;
            float p2 = __expf(fmaf(sc2[j][2], sfac, mv[2])) * inv_l;
            float p3 = __expf(fmaf(sc2[j][3], sfac, mv[3])) * inv_l;
            f32x4 pv; pv[0] = p0; pv[1] = p1; pv[2] = p2; pv[3] = p3;
            __builtin_nontemporal_store(pv, (f32x4*)(probs + pbase + j * 16));
            uint2 pq; pq.x = cvtpk_bf16(p0, p1); pq.y = cvtpk_bf16(p2, p3);
            *(uint2*)(psrow + ((j * 32 + quad * 8) ^ sx16)) = pq;
        }
        // first-half V fragments (tile kt) — independent of the Ps fence
        const char* vbl = VtsB + ob0;
        short8 vv[4];
        #pragma unroll
        for (int j2 = 0; j2 < 4; j2++)
            vv[j2] = *(const short8*)(vbl + (j2 * 16 + l16) * 128 + ((quad << 4) ^ sx16));
        f32x4 scn[4] = {};
        if (kt < 31) QKT(scn, ob1);          // next-tile QK^T overlaps the VALU above
        // --- fence: this wave's Ps writes visible ---
        asm volatile("s_waitcnt lgkmcnt(0)" ::: "memory");
        __builtin_amdgcn_sched_barrier(0);
        short8 aP0 = *(const short8*)(psrow + ((quad << 4) ^ sx16));
        short8 aP1 = *(const short8*)(psrow + ((64 + (quad << 4)) ^ sx16));
        __builtin_amdgcn_s_setprio(1);
        #pragma unroll
        for (int j2 = 0; j2 < 4; j2++) oacc[j2] = MFMA16(aP0, vv[j2], oacc[j2]);
        __builtin_amdgcn_s_setprio(0);
        #pragma unroll
        for (int j2 = 0; j2 < 4; j2++)
            vv[j2] = *(const short8*)(vbl + (j2 * 16 + l16) * 128 + ((64 + (quad << 4)) ^ sx16));
        __builtin_amdgcn_s_setprio(1);
        #pragma unroll
        for (int j2 = 0; j2 < 4; j2++) oacc[j2] = MFMA16(aP1, vv[j2], oacc[j2]);
        __builtin_amdgcn_s_setprio(0);
        // counted wait: forces prior-iter stages; leaves this iter's 4 probs stores in flight
        asm volatile("s_waitcnt vmcnt(4)" ::: "memory");
        __builtin_amdgcn_s_barrier();
        int tmp = ob0; ob0 = ob1; ob1 = ob2; ob2 = tmp;
        #pragma unroll
        for (int j = 0; j < 4; j++) sc2[j] = scn[j];
    }
#undef STAGE_K
#undef STAGE_V
#undef QKT
    #pragma unroll
    for (int j2 = 0; j2 < 4; j2++)
        #pragma unroll
        for (int r = 0; r < 4; r++) {
            int qr = q0 + wave * 16 + quad * 4 + r;
            ctx[((size_t)b * 2048 + qr) * 1024 + h * 64 + j2 * 16 + l16] = f2bf(oacc[j2][r]);
        }
}

extern "C" void kernel_launch(void* const* d_in, const int* in_sizes, int n_in,
                              void* d_out, int out_size, void* d_ws, size_t ws_size,
                              hipStream_t stream) {
    const float* X    = (const float*)d_in[0];
    const int*  amask = (const int*)d_in[1];
    const int*  stp   = (const int*)d_in[2];
    const float* Wq   = (const float*)d_in[3];
    const float* bq   = (const float*)d_in[4];
    const float* Wk   = (const float*)d_in[5];
    const float* bk   = (const float*)d_in[6];
    const float* Wv   = (const float*)d_in[7];
    const float* bv   = (const float*)d_in[8];
    const float* Wo   = (const float*)d_in[9];
    const float* bo   = (const float*)d_in[10];
    const float* sw   = (const float*)d_in[11];

    float* out   = (float*)d_out;
    float* probs = out + 4194304;          // (2,16,2048,2048) fp32

    char* ws = (char*)d_ws;
    unsigned short* Xb    = (unsigned short*)(ws);               // 8 MB
    unsigned short* WqkvT = (unsigned short*)(ws + 8388608);     // 6 MB
    unsigned short* WoT   = (unsigned short*)(ws + 14680064);    // 2 MB
    float*          biasq = (float*)(ws + 16777216);             // 12 KB
    unsigned short* Qb    = (unsigned short*)(ws + 16789504);    // 8 MB (Q,K contiguous)
    unsigned short* Vtb   = (unsigned short*)(ws + 41955328);    // 8 MB (V^T, written by gemm_qkv)
    unsigned short* Ctx   = (unsigned short*)(ws + 50343936);    // 8 MB
    unsigned short* Kb    = Qb + 4194304;

    prep<<<8193, 256, 0, stream>>>(X, Xb, Wq, Wk, Wv, Wo, WqkvT, WoT, bq, bk, bv, biasq);
    gemm_qkv<<<dim3(32, 24), 256, 0, stream>>>(Xb, WqkvT, biasq, Qb, Vtb);
    attn<<<dim3(16, 32), 512, 0, stream>>>(Qb, Kb, Vtb, amask, stp, sw, probs, Ctx);
    gemm_out<<<dim3(64, 8), 256, 0, stream>>>(Ctx, WoT, bo, out);
}